// Round 12
// baseline (120.326 us; speedup 1.0000x reference)
//
#include <hip/hip_runtime.h>

// SNN classifier: T=500, B=256, 96 -> 64 -> 80, leaky (subtract reset).
// f32 BLAS-order arithmetic replicated exactly (single-accumulator
// k-ascending __fmaf_rn chains; fixed leaky op-sequence) -> outputs
// bitwise-identical to the passing round-2..11 kernels.
//
// Round-12: round-11's DS-only structure worked (103us; kernels left the
// top-5). Remaining cost: W-broadcast ds_read_b128 count is independent of
// o-slicing and only amortizes over t-rows per lane (P). P=1 -> 3.07M (K1)
// + 2.56M (K3) broadcast instrs. This round: P=4 register t-tiling
// (acc[4][16] / acc[4][20], static indices), broadcasts /4. LDS stays
// <=64KB static via k-passes (K1: 4x24k, K3: 2x32k), x/spk tile stride 36
// dwords (==4 mod 32, conflict-free-optimal b128). W1/W2 fully LDS-resident.
// Grid 125*4 blocks (500/4 t-quads exact), 2 blocks/CU, 8 waves/CU.
// K2/K4 untouched.

#define T_STEPS 500
#define BATCH   256
#define N_IN    96
#define N_HID   64
#define N_OUT   80
#define CH      50    // chunk size in K2/K4 (500 = 10*50)

// ---------------- K1: cur1 = x @ W1 + b1 ----------------
// grid 125*4, block 256 (4 waves = 4 16-h slices). Block = (t-quad, 64-b).
// LDS: xs 4x64 rows x 36 (24k-pass) = 36.9KB + W1 24.6KB = 61.4KB.
__global__ __launch_bounds__(256) void k1_cur1(
    const float* __restrict__ x,   // (T,B,96)
    const float* __restrict__ W1,  // (96,64)
    const float* __restrict__ b1,  // (64)
    float* __restrict__ cur1)      // (T,B,64) region inside outs
{
    const int tq   = blockIdx.x >> 2;        // 0..124 (t = tq*4+p)
    const int b0   = (blockIdx.x & 3) << 6;
    const int lane = threadIdx.x & 63;       // = local b
    const int w    = threadIdx.x >> 6;       // wave id
    const int o0   = w << 4;                 // 16-h slice

    __shared__ float xs[4 * 64 * 36];        // rows (p,b), stride 36 (==4 mod 32)
    __shared__ float ws[96 * 64];            // W1 [k][h]

    // stage W1 once (coalesced, linear)
    {
        const float4* __restrict__ srcw = reinterpret_cast<const float4*>(W1);
        #pragma unroll
        for (int ii = 0; ii < 6; ++ii) {
            const int i = ii * 256 + threadIdx.x;
            *reinterpret_cast<float4*>(&ws[i * 4]) = srcw[i];
        }
    }

    float acc[4][16];
    #pragma unroll
    for (int p = 0; p < 4; ++p)
        #pragma unroll
        for (int o = 0; o < 16; ++o) acc[p][o] = 0.0f;

    #pragma unroll 1
    for (int kq = 0; kq < 4; ++kq) {         // four 24-k passes
        const int k0 = kq * 24;
        __syncthreads();                     // xs free (prev pass consumed) / ws staged
        // ---- stage xs: rows (p,b) <- x[tq*4+p][b0+b][k0..k0+23]
        #pragma unroll
        for (int ii = 0; ii < 6; ++ii) {
            const int i   = ii * 256 + threadIdx.x;   // f4 granule 0..1535
            const int row = i / 6;                    // p*64 + b
            const int g   = i % 6;
            const int p   = row >> 6, bb = row & 63;
            const float4 v = *reinterpret_cast<const float4*>(
                x + ((size_t)(tq * 4 + p) * BATCH + b0 + bb) * N_IN + k0 + g * 4);
            *reinterpret_cast<float4*>(&xs[row * 36 + g * 4]) = v;
        }
        __syncthreads();
        // ---- compute pass (DS-only inner loop)
        #pragma unroll
        for (int kg = 0; kg < 6; ++kg) {
            float4 xv[4];
            #pragma unroll
            for (int p = 0; p < 4; ++p)
                xv[p] = *reinterpret_cast<const float4*>(
                    &xs[(p * 64 + lane) * 36 + kg * 4]);
            #pragma unroll
            for (int j = 0; j < 4; ++j) {
                const int k = k0 + kg * 4 + j;
                const float4* __restrict__ wr =       // LDS broadcast
                    reinterpret_cast<const float4*>(&ws[k * 64 + o0]);
                const float4 w0 = wr[0], w1 = wr[1], w2 = wr[2], w3 = wr[3];
                const float wv[16] = {w0.x, w0.y, w0.z, w0.w,
                                      w1.x, w1.y, w1.z, w1.w,
                                      w2.x, w2.y, w2.z, w2.w,
                                      w3.x, w3.y, w3.z, w3.w};
                #pragma unroll
                for (int p = 0; p < 4; ++p) {
                    const float xsc = (j == 0) ? xv[p].x : (j == 1) ? xv[p].y
                                    : (j == 2) ? xv[p].z : xv[p].w;
                    #pragma unroll
                    for (int o = 0; o < 16; ++o)
                        acc[p][o] = __fmaf_rn(xsc, wv[o], acc[p][o]);
                }
            }
        }
    }

    // ---- bias + direct per-lane stores
    #pragma unroll
    for (int p = 0; p < 4; ++p) {
        float* dst = cur1 + ((size_t)(tq * 4 + p) * BATCH + b0 + lane) * N_HID + o0;
        #pragma unroll
        for (int o4 = 0; o4 < 4; ++o4) {
            float4 v;
            v.x = __fadd_rn(acc[p][o4 * 4 + 0], b1[o0 + o4 * 4 + 0]);
            v.y = __fadd_rn(acc[p][o4 * 4 + 1], b1[o0 + o4 * 4 + 1]);
            v.z = __fadd_rn(acc[p][o4 * 4 + 2], b1[o0 + o4 * 4 + 2]);
            v.w = __fadd_rn(acc[p][o4 * 4 + 3], b1[o0 + o4 * 4 + 3]);
            reinterpret_cast<float4*>(dst)[o4] = v;
        }
    }
}

// ---------------- K2: layer-1 recurrence (in-place cur1 -> spk) ----------------
__global__ __launch_bounds__(64) void k2_rec1(float* cs)  // outs region
{
    const int b = blockIdx.x;
    const int h = threadIdx.x;
    const size_t str  = (size_t)BATCH * N_HID;
    const size_t base = (size_t)b * N_HID + h;

    float A[CH], Bv[CH];
    #pragma unroll
    for (int i = 0; i < CH; ++i) A[i] = cs[(size_t)i * str + base];

    float mem = 0.f, s = 0.f;
    for (int cp = 0; cp < 5; ++cp) {            // 10 chunks, processed in pairs
        const int c0 = 2 * cp;
        #pragma unroll
        for (int i = 0; i < CH; ++i)            // prefetch chunk c0+1
            Bv[i] = cs[(size_t)((c0 + 1) * CH + i) * str + base];
        #pragma unroll
        for (int i = 0; i < CH; ++i) {          // compute chunk c0 from A
            const float m = __fsub_rn(__fadd_rn(__fmul_rn(0.95f, mem), A[i]), s);
            mem = m; s = (m > 1.0f) ? 1.0f : 0.0f;
            cs[(size_t)(c0 * CH + i) * str + base] = s;
        }
        if (cp < 4) {
            #pragma unroll
            for (int i = 0; i < CH; ++i)        // prefetch chunk c0+2
                A[i] = cs[(size_t)((c0 + 2) * CH + i) * str + base];
        }
        #pragma unroll
        for (int i = 0; i < CH; ++i) {          // compute chunk c0+1 from Bv
            const float m = __fsub_rn(__fadd_rn(__fmul_rn(0.95f, mem), Bv[i]), s);
            mem = m; s = (m > 1.0f) ? 1.0f : 0.0f;
            cs[(size_t)((c0 + 1) * CH + i) * str + base] = s;
        }
    }
}

// ---------------- K3: cur2 = spk @ W2 + b2 ----------------
// grid 125*4, block 256 (4 waves = 4 20-o slices). Block = (t-quad, 64-b).
// LDS: xs 4x64 rows x 36 (32k-pass) = 36.9KB + W2 20.5KB = 57.3KB.
__global__ __launch_bounds__(256) void k3_cur2(
    const float* __restrict__ spk,  // (T,B,64) in outs
    const float* __restrict__ W2,   // (64,80)
    const float* __restrict__ b2,   // (80)
    float* __restrict__ cur2)       // (T,B,80) = outm region
{
    const int tq   = blockIdx.x >> 2;        // 0..124
    const int b0   = (blockIdx.x & 3) << 6;
    const int lane = threadIdx.x & 63;       // = local b
    const int w    = threadIdx.x >> 6;       // wave id
    const int o0   = w * 20;                 // 20-o slice

    __shared__ float xs[4 * 64 * 36];        // rows (p,b), stride 36
    __shared__ float ws[64 * 80];            // W2 [k][o]

    // stage W2 once (coalesced, linear)
    {
        const float4* __restrict__ srcw = reinterpret_cast<const float4*>(W2);
        #pragma unroll
        for (int ii = 0; ii < 5; ++ii) {
            const int i = ii * 256 + threadIdx.x;
            *reinterpret_cast<float4*>(&ws[i * 4]) = srcw[i];
        }
    }

    float acc[4][20];
    #pragma unroll
    for (int p = 0; p < 4; ++p)
        #pragma unroll
        for (int o = 0; o < 20; ++o) acc[p][o] = 0.0f;

    #pragma unroll 1
    for (int kq = 0; kq < 2; ++kq) {         // two 32-k passes
        const int k0 = kq * 32;
        __syncthreads();
        // ---- stage xs: rows (p,b) <- spk[tq*4+p][b0+b][k0..k0+31]
        #pragma unroll
        for (int ii = 0; ii < 8; ++ii) {
            const int i   = ii * 256 + threadIdx.x;   // f4 granule 0..2047
            const int row = i >> 3;                   // p*64 + b
            const int g   = i & 7;
            const int p   = row >> 6, bb = row & 63;
            const float4 v = *reinterpret_cast<const float4*>(
                spk + ((size_t)(tq * 4 + p) * BATCH + b0 + bb) * N_HID + k0 + g * 4);
            *reinterpret_cast<float4*>(&xs[row * 36 + g * 4]) = v;
        }
        __syncthreads();
        // ---- compute pass (DS-only inner loop)
        #pragma unroll
        for (int kg = 0; kg < 8; ++kg) {
            float4 xv[4];
            #pragma unroll
            for (int p = 0; p < 4; ++p)
                xv[p] = *reinterpret_cast<const float4*>(
                    &xs[(p * 64 + lane) * 36 + kg * 4]);
            #pragma unroll
            for (int j = 0; j < 4; ++j) {
                const int k = k0 + kg * 4 + j;
                const float4* __restrict__ wr =       // LDS broadcast
                    reinterpret_cast<const float4*>(&ws[k * 80 + o0]);
                const float4 w0 = wr[0], w1 = wr[1], w2 = wr[2], w3 = wr[3], w4 = wr[4];
                const float wv[20] = {w0.x, w0.y, w0.z, w0.w,
                                      w1.x, w1.y, w1.z, w1.w,
                                      w2.x, w2.y, w2.z, w2.w,
                                      w3.x, w3.y, w3.z, w3.w,
                                      w4.x, w4.y, w4.z, w4.w};
                #pragma unroll
                for (int p = 0; p < 4; ++p) {
                    const float sv = (j == 0) ? xv[p].x : (j == 1) ? xv[p].y
                                   : (j == 2) ? xv[p].z : xv[p].w;
                    #pragma unroll
                    for (int o = 0; o < 20; ++o)
                        acc[p][o] = __fmaf_rn(sv, wv[o], acc[p][o]);
                }
            }
        }
    }

    // ---- bias + direct per-lane stores
    #pragma unroll
    for (int p = 0; p < 4; ++p) {
        float* dst = cur2 + ((size_t)(tq * 4 + p) * BATCH + b0 + lane) * N_OUT + o0;
        #pragma unroll
        for (int o4 = 0; o4 < 5; ++o4) {
            float4 v;
            v.x = __fadd_rn(acc[p][o4 * 4 + 0], b2[o0 + o4 * 4 + 0]);
            v.y = __fadd_rn(acc[p][o4 * 4 + 1], b2[o0 + o4 * 4 + 1]);
            v.z = __fadd_rn(acc[p][o4 * 4 + 2], b2[o0 + o4 * 4 + 2]);
            v.w = __fadd_rn(acc[p][o4 * 4 + 3], b2[o0 + o4 * 4 + 3]);
            reinterpret_cast<float4*>(dst)[o4] = v;
        }
    }
}

// ---------------- K4: layer-2 recurrence (cur2 in outm -> spk/mem finals) ----------------
__global__ __launch_bounds__(80) void k4_rec2(float* cm, float* os)
{
    const int b = blockIdx.x;
    const int o = threadIdx.x;   // 0..79
    const size_t str  = (size_t)BATCH * N_OUT;
    const size_t base = (size_t)b * N_OUT + o;

    float A[CH], Bv[CH];
    #pragma unroll
    for (int i = 0; i < CH; ++i) A[i] = cm[(size_t)i * str + base];

    float mem = 0.f, s = 0.f;
    for (int cp = 0; cp < 5; ++cp) {
        const int c0 = 2 * cp;
        #pragma unroll
        for (int i = 0; i < CH; ++i)
            Bv[i] = cm[(size_t)((c0 + 1) * CH + i) * str + base];
        #pragma unroll
        for (int i = 0; i < CH; ++i) {
            const int t = c0 * CH + i;
            const float m = __fsub_rn(__fadd_rn(__fmul_rn(0.95f, mem), A[i]), s);
            mem = m; s = (m > 1.0f) ? 1.0f : 0.0f;
            os[(size_t)t * str + base] = s;
            cm[(size_t)t * str + base] = m;
        }
        if (cp < 4) {
            #pragma unroll
            for (int i = 0; i < CH; ++i)
                A[i] = cm[(size_t)((c0 + 2) * CH + i) * str + base];
        }
        #pragma unroll
        for (int i = 0; i < CH; ++i) {
            const int t = (c0 + 1) * CH + i;
            const float m = __fsub_rn(__fadd_rn(__fmul_rn(0.95f, mem), Bv[i]), s);
            mem = m; s = (m > 1.0f) ? 1.0f : 0.0f;
            os[(size_t)t * str + base] = s;
            cm[(size_t)t * str + base] = m;
        }
    }
}

extern "C" void kernel_launch(void* const* d_in, const int* in_sizes, int n_in,
                              void* d_out, int out_size, void* d_ws, size_t ws_size,
                              hipStream_t stream) {
    const float* x  = (const float*)d_in[0];
    const float* W1 = (const float*)d_in[1];
    const float* b1 = (const float*)d_in[2];
    const float* W2 = (const float*)d_in[3];
    const float* b2 = (const float*)d_in[4];
    float* outs = (float*)d_out;                                   // (T,B,80) spikes
    float* outm = outs + (size_t)T_STEPS * BATCH * N_OUT;          // (T,B,80) mem

    k1_cur1<<<125 * 4, 256, 0, stream>>>(x, W1, b1, outs);         // cur1 -> outs
    k2_rec1<<<BATCH, 64, 0, stream>>>(outs);                       // spk overwrites cur1
    k3_cur2<<<125 * 4, 256, 0, stream>>>(outs, W2, b2, outm);      // cur2 -> outm
    k4_rec2<<<BATCH, 80, 0, stream>>>(outm, outs);                 // finals in place
}